// Round 1
// baseline (352.874 us; speedup 1.0000x reference)
//
#include <hip/hip_runtime.h>
#include <math.h>

#define HIDDEN 128

// ---------------------------------------------------------------------------
// Kernel A: per-(b,n) node row.
//   coef[r]  = sigmoid( gelu(z[r]@W1 + b1) @ W2 + b2 )   (depends only on src node!)
//   areas[r] = softplus( z[r]@Wa + ba )
//   net[r]   = rainfall[r]                                (init for scatter)
// One 64-lane wave per row. W1 column (per-lane) cached in 128 VGPRs.
// ---------------------------------------------------------------------------
__global__ __launch_bounds__(256) void node_coef_kernel(
    const float* __restrict__ z,     // [R][128]
    const float* __restrict__ rain,  // [R]
    const float* __restrict__ W1,    // [128][64]
    const float* __restrict__ b1,    // [64]
    const float* __restrict__ W2,    // [64]
    const float* __restrict__ b2,    // [1]
    const float* __restrict__ Wa,    // [128]
    const float* __restrict__ ba,    // [1]
    float* __restrict__ coef,        // [R]
    float* __restrict__ areas,       // [R]
    float* __restrict__ net,         // [R]
    int R)
{
    const int lane   = threadIdx.x & 63;
    const int wave   = blockIdx.x * (blockDim.x >> 6) + (threadIdx.x >> 6);
    const int nwaves = gridDim.x * (blockDim.x >> 6);

    // Per-lane register cache of W1 column `lane`: w1[h] = W1[h][lane]
    float w1a[64], w1b[64];
#pragma unroll
    for (int h = 0; h < 64; ++h) w1a[h] = W1[h * 64 + lane];
#pragma unroll
    for (int h = 0; h < 64; ++h) w1b[h] = W1[(h + 64) * 64 + lane];

    const float wa0 = Wa[lane];
    const float wa1 = Wa[64 + lane];
    const float b1l = b1[lane];
    const float w2l = W2[lane];
    const float b2s = b2[0];
    const float bas = ba[0];

    int r = wave;
    float z0 = 0.f, z1 = 0.f;
    if (r < R) {
        z0 = z[(size_t)r * HIDDEN + lane];
        z1 = z[(size_t)r * HIDDEN + 64 + lane];
    }

    for (; r < R; r += nwaves) {
        // software prefetch next row's z
        const int rn = r + nwaves;
        float z0n = 0.f, z1n = 0.f;
        if (rn < R) {
            z0n = z[(size_t)rn * HIDDEN + lane];
            z1n = z[(size_t)rn * HIDDEN + 64 + lane];
        }

        float acc = 0.f;
#pragma unroll
        for (int h = 0; h < 64; ++h) {
            const float zh = __shfl(z0, h, 64);   // v_readlane broadcast
            acc = fmaf(zh, w1a[h], acc);
        }
#pragma unroll
        for (int h = 0; h < 64; ++h) {
            const float zh = __shfl(z1, h, 64);
            acc = fmaf(zh, w1b[h], acc);
        }

        // exact gelu: 0.5*x*(1+erf(x/sqrt(2)))
        const float x = acc + b1l;
        const float g = 0.5f * x * (1.0f + erff(x * 0.70710678118654752f));

        float sp = g * w2l;                   // partial of hmid @ W2
        float pa = fmaf(z0, wa0, z1 * wa1);   // partial of z @ Wa

        // butterfly reduce both sums across the 64-lane wave
#pragma unroll
        for (int off = 32; off > 0; off >>= 1) {
            sp += __shfl_xor(sp, off, 64);
            pa += __shfl_xor(pa, off, 64);
        }

        if (lane == 0) {
            const float s = sp + b2s;
            const float c = 1.0f / (1.0f + expf(-s));   // sigmoid
            const float ad = pa + bas;
            // stable softplus: max(x,0) + log1p(exp(-|x|))
            const float ar = fmaxf(ad, 0.f) + log1pf(expf(-fabsf(ad)));
            coef[r]  = c;
            areas[r] = ar;
            net[r]   = rain[r];
        }

        z0 = z0n;
        z1 = z1n;
    }
}

// ---------------------------------------------------------------------------
// Kernel B: per-edge. flows + scatter net[dst]+=f, net[src]-=f
// (inflow - outflow algebraically reduces to a single signed add per endpoint)
// ---------------------------------------------------------------------------
__global__ __launch_bounds__(256) void edge_kernel(
    const int* __restrict__ eidx,    // [2][E] int32
    const float* __restrict__ h,     // [B][N]
    const float* __restrict__ coef,  // [B][N]
    float* __restrict__ flows,       // [B][E]
    float* __restrict__ net,         // [B][N]
    int E, int N)
{
    const int e = blockIdx.x * blockDim.x + threadIdx.x;
    if (e >= E) return;
    const int s = eidx[e];
    const int d = eidx[E + e];

#pragma unroll
    for (int b = 0; b < 2; ++b) {
        const int off = b * N;
        const float dh = h[off + s] - h[off + d];
        const float sg = (dh > 0.f) ? 1.f : ((dh < 0.f) ? -1.f : 0.f);
        float f = coef[off + s] * sg * sqrtf(fabsf(dh) + 1e-6f);
        f = fminf(fmaxf(f, -10.0f), 10.0f);
        flows[(size_t)b * E + e] = f;
        if (f != 0.0f) {
            unsafeAtomicAdd(&net[off + d],  f);
            unsafeAtomicAdd(&net[off + s], -f);
        }
    }
}

// ---------------------------------------------------------------------------
// Kernel C: h_new = h + clip(DT*net/(areas+1e-6), -1, 1)
// ---------------------------------------------------------------------------
__global__ __launch_bounds__(256) void update_kernel(
    const float* __restrict__ h,
    const float* __restrict__ net,
    const float* __restrict__ areas,
    float* __restrict__ hnew,
    int R)
{
    const int r = blockIdx.x * blockDim.x + threadIdx.x;
    if (r >= R) return;
    float dh = 300.0f * net[r] / (areas[r] + 1e-6f);
    dh = fminf(fmaxf(dh, -1.0f), 1.0f);
    hnew[r] = h[r] + dh;
}

extern "C" void kernel_launch(void* const* d_in, const int* in_sizes, int n_in,
                              void* d_out, int out_size, void* d_ws, size_t ws_size,
                              hipStream_t stream)
{
    const float* h    = (const float*)d_in[0];
    const float* z    = (const float*)d_in[1];
    const int*   eidx = (const int*)  d_in[2];
    // d_in[3] edge_type: unused by reference
    const float* rain = (const float*)d_in[4];
    const float* W1   = (const float*)d_in[5];
    const float* b1   = (const float*)d_in[6];
    const float* W2   = (const float*)d_in[7];
    const float* b2   = (const float*)d_in[8];
    const float* Wa   = (const float*)d_in[9];
    const float* ba   = (const float*)d_in[10];

    const int R = in_sizes[0];      // B*N
    const int E = in_sizes[3];      // edge count (edge_type has E elements)
    const int B = 2;
    const int N = R / B;

    float* out_h     = (float*)d_out;       // [B*N]
    float* out_flows = out_h + R;           // [B*E]

    float* coef  = (float*)d_ws;            // [R]
    float* areas = coef + R;                // [R]
    float* net   = areas + R;               // [R]

    // Kernel A: 512 blocks x 256 thr = 2048 waves, ~49 rows each
    node_coef_kernel<<<512, 256, 0, stream>>>(z, rain, W1, b1, W2, b2, Wa, ba,
                                              coef, areas, net, R);
    edge_kernel<<<(E + 255) / 256, 256, 0, stream>>>(eidx, h, coef,
                                                     out_flows, net, E, N);
    update_kernel<<<(R + 255) / 256, 256, 0, stream>>>(h, net, areas, out_h, R);
}